// Round 3
// baseline (301.039 us; speedup 1.0000x reference)
//
#include <hip/hip_runtime.h>
#include <hip/hip_bf16.h>

typedef __attribute__((ext_vector_type(8))) short bf16x8;   // 8 bf16 = 4 VGPRs
typedef __attribute__((ext_vector_type(4))) float f32x4;

__device__ __forceinline__ short f2bf(float v) {
    unsigned u = __builtin_bit_cast(unsigned, v);
    u += 0x7fffu + ((u >> 16) & 1u);          // round-to-nearest-even
    return (short)(u >> 16);
}
__device__ __forceinline__ float relu(float v) { return v > 0.f ? v : 0.f; }

// ---------------- prep: build bf16 W-fragments into d_ws ----------------
// Slot (mt=j*8+ot, kt, lane): lane l holds W[o = ot*16 + (l&15)][c = kt*32 + (l>>4)*8 + e].
// Used as the MFMA *B* operand (same (group,elem)->k map as the X/A operand, so the
// hardware k-permutation cancels — proven by R1/R2 passing).
__global__ __launch_bounds__(64)
void prep_wfrag(const float* __restrict__ w, bf16x8* __restrict__ wf) {
    const int mt   = blockIdx.x >> 2;       // 0..39
    const int kt   = blockIdx.x & 3;        // 0..3
    const int lane = threadIdx.x;           // 0..63
    const int j  = mt >> 3;
    const int ot = mt & 7;
    const int o  = ot * 16 + (lane & 15);
    const int c0 = kt * 32 + (lane >> 4) * 8;
    const float* wp = w + ((size_t)o * 128 + c0) * 5 + j;
    bf16x8 f;
    #pragma unroll
    for (int e = 0; e < 8; ++e) f[e] = f2bf(wp[e * 5]);
    wf[(size_t)(mt * 4 + kt) * 64 + lane] = f;
}

// ---------------- main: one block per (n, h) row ----------------
// 512 threads = 8 waves = 2 ot-halves x 4 pos-tiles (16 w each).
// Y[j,o](h,w) = sum_c W_j[o,c] x[c,h,w]  (unshifted GEMM), tap shift folded into
// the store. Operands: A = X (M = 16 positions), B = W (N = 16 channels), so
// D row = position (contiguous w) -> float4 stores for j=0,2,4.
__global__ __launch_bounds__(512)
void sconv_main(const float* __restrict__ x, const bf16x8* __restrict__ wf,
                float* __restrict__ out) {
    const int bid = blockIdx.x;
    const int h = bid & 63;
    const int n = bid >> 6;

    const int t    = threadIdx.x;
    const int wave = t >> 6;
    const int lane = t & 63;
    const int mh   = wave >> 2;             // which half of the 8 ot-tiles
    const int pt   = wave & 3;              // which 16 positions
    const int l15  = lane & 15;
    const int lg   = lane >> 4;
    const int pos  = pt * 16 + l15;         // gather position (A row)

    // ---- gather X fragments (A operand), all in-bounds, kept in regs ----
    // lane l holds X[c = kt*32 + lg*8 + e][pos]
    const float* xb = x + (size_t)n * 128 * 4096 + (size_t)(h * 64 + pos);
    bf16x8 xf[4];
    #pragma unroll
    for (int kt = 0; kt < 4; ++kt) {
        const float* xp = xb + (size_t)(kt * 32 + lg * 8) * 4096;
        bf16x8 f;
        #pragma unroll
        for (int e = 0; e < 8; ++e) f[e] = f2bf(xp[(size_t)e * 4096]);
        xf[kt] = f;
    }

    const int wp0 = pt * 16 + lg * 4;       // first store position (D row base)

    #pragma unroll
    for (int j = 0; j < 5; ++j) {
        #pragma unroll
        for (int oi = 0; oi < 4; ++oi) {
            const int ot = mh * 4 + oi;
            const bf16x8* afp = wf + (size_t)((j * 8 + ot) * 4) * 64 + lane;

            f32x4 acc = {0.f, 0.f, 0.f, 0.f};
            #pragma unroll
            for (int kt = 0; kt < 4; ++kt)
                acc = __builtin_amdgcn_mfma_f32_16x16x32_bf16(
                    xf[kt], afp[(size_t)kt * 64], acc, 0, 0, 0);

            const int oc = ot * 16 + l15;   // D col = channel
            float* ob = out + (((size_t)n * 640 + j * 128 + oc) * 64) * 64;

            if (j == 2) {
                f32x4 v;
                #pragma unroll
                for (int r = 0; r < 4; ++r) v[r] = relu(acc[r]);
                __builtin_nontemporal_store(
                    v, reinterpret_cast<f32x4*>(ob + h * 64 + wp0));
            } else if (j == 0 || j == 4) {
                // row-shifted store: j=0 -> row h+1 (h==63 wraps to row 0, zero-fill)
                //                    j=4 -> row h-1 (h==0 wraps to row 63, zero-fill)
                const int  hs = (j == 0) ? ((h + 1) & 63) : ((h + 63) & 63);
                const bool zr = (j == 0) ? (h == 63) : (h == 0);
                f32x4 v;
                #pragma unroll
                for (int r = 0; r < 4; ++r) v[r] = zr ? 0.f : relu(acc[r]);
                __builtin_nontemporal_store(
                    v, reinterpret_cast<f32x4*>(ob + hs * 64 + wp0));
            } else {
                // col-shifted store (unaligned): j=1 -> w+1 (w==63 wraps, zero)
                //                                j=3 -> w-1 (w==0 wraps, zero)
                #pragma unroll
                for (int r = 0; r < 4; ++r) {
                    const int w  = wp0 + r;
                    const int ws = (j == 1) ? ((w + 1) & 63) : ((w + 63) & 63);
                    const bool z = (j == 1) ? (w == 63) : (w == 0);
                    __builtin_nontemporal_store(
                        z ? 0.f : relu(acc[r]), ob + h * 64 + ws);
                }
            }
        }
    }
}

// ---------------- fallback (R1 kernel) if workspace is too small ----------------
__global__ __launch_bounds__(512, 2)
void sconv_mfma(const float* __restrict__ x, const float* __restrict__ w,
                float* __restrict__ out) {
    __shared__ bf16x8 wfrag[8][4][64];
    const int bid = blockIdx.x;
    const int j   = bid % 5;
    const int hp  = (bid / 5) % 32;
    const int n   = bid / 160;
    const int t = threadIdx.x;
    for (int s = t; s < 2048; s += 512) {
        const int lane = s & 63;
        const int rest = s >> 6;
        const int mt   = rest >> 2;
        const int kt   = rest & 3;
        const int o    = mt * 16 + (lane & 15);
        const int c0   = kt * 32 + (lane >> 4) * 8;
        const float* wp = w + ((size_t)o * 128 + c0) * 5 + j;
        bf16x8 f;
        #pragma unroll
        for (int e = 0; e < 8; ++e) f[e] = f2bf(wp[e * 5]);
        wfrag[mt][kt][lane] = f;
    }
    __syncthreads();
    const int wave = t >> 6;
    const int lane = t & 63;
    const int l15  = lane & 15;
    const int lg   = lane >> 4;
    const int h    = hp * 2 + (wave >> 2);
    const int wcol = (wave & 3) * 16 + l15;
    const int dy[5] = {-1, 0, 0, 0, 1};
    const int dx[5] = { 0,-1, 0, 1, 0};
    const int hi = h + dy[j];
    const int wi = wcol + dx[j];
    const bool valid = ((unsigned)hi < 64u) && ((unsigned)wi < 64u);
    const int hic = hi < 0 ? 0 : (hi > 63 ? 63 : hi);
    const int wic = wi < 0 ? 0 : (wi > 63 ? 63 : wi);
    const float* xb = x + (size_t)n * 128 * 4096 + (size_t)(hic * 64 + wic);
    bf16x8 xf[4];
    #pragma unroll
    for (int kt = 0; kt < 4; ++kt) {
        const int c0 = kt * 32 + lg * 8;
        const float* xp = xb + (size_t)c0 * 4096;
        bf16x8 f;
        #pragma unroll
        for (int e = 0; e < 8; ++e) {
            float v = xp[(size_t)e * 4096];
            f[e] = f2bf(valid ? v : 0.0f);
        }
        xf[kt] = f;
    }
    f32x4 acc[8];
    #pragma unroll
    for (int mt = 0; mt < 8; ++mt) acc[mt] = f32x4{0.f, 0.f, 0.f, 0.f};
    #pragma unroll
    for (int kt = 0; kt < 4; ++kt)
        #pragma unroll
        for (int mt = 0; mt < 8; ++mt)
            acc[mt] = __builtin_amdgcn_mfma_f32_16x16x32_bf16(
                wfrag[mt][kt][lane], xf[kt], acc[mt], 0, 0, 0);
    float* ob = out + ((size_t)n * 640 + (size_t)j * 128) * 4096
                    + (size_t)(h * 64 + wcol);
    #pragma unroll
    for (int mt = 0; mt < 8; ++mt) {
        const int ch = mt * 16 + lg * 4;
        #pragma unroll
        for (int r = 0; r < 4; ++r) {
            float v = acc[mt][r];
            ob[(size_t)(ch + r) * 4096] = v > 0.f ? v : 0.f;
        }
    }
}

extern "C" void kernel_launch(void* const* d_in, const int* in_sizes, int n_in,
                              void* d_out, int out_size, void* d_ws, size_t ws_size,
                              hipStream_t stream) {
    const float* x = (const float*)d_in[0];   // [32,128,64,64] f32
    const float* w = (const float*)d_in[1];   // [128,128,5] f32
    float* out = (float*)d_out;               // [32,640,64,64] f32

    const size_t wf_bytes = (size_t)40 * 4 * 64 * sizeof(bf16x8);  // 160 KiB
    if (ws_size >= wf_bytes) {
        bf16x8* wf = (bf16x8*)d_ws;
        hipLaunchKernelGGL(prep_wfrag, dim3(160), dim3(64), 0, stream, w, wf);
        hipLaunchKernelGGL(sconv_main, dim3(32 * 64), dim3(512), 0, stream,
                           x, wf, out);
    } else {
        hipLaunchKernelGGL(sconv_mfma, dim3(32 * 32 * 5), dim3(512), 0, stream,
                           x, w, out);
    }
}

// Round 4
// 80.097 us; speedup vs baseline: 3.7584x; 3.7584x over previous
//
#include <hip/hip_runtime.h>
#include <hip/hip_bf16.h>

typedef __attribute__((ext_vector_type(8))) short bf16x8;   // 8 bf16 = 4 VGPRs
typedef __attribute__((ext_vector_type(4))) float f32x4;

__device__ __forceinline__ short f2bf(float v) {
    unsigned u = __builtin_bit_cast(unsigned, v);
    u += 0x7fffu + ((u >> 16) & 1u);          // round-to-nearest-even
    return (short)(u >> 16);
}
__device__ __forceinline__ float relu(float v) { return v > 0.f ? v : 0.f; }

// ---------------- prep: build bf16 W-fragments into d_ws ----------------
// Slot (mt=j*8+ot, kt, lane): lane l holds W[o = ot*16 + (l&15)][c = kt*32 + (l>>4)*8 + e].
// Same (group,elem)->k map as the X operand so the HW k-permutation cancels
// (numerically verified in R1/R2/R3).
__global__ __launch_bounds__(64)
void prep_wfrag(const float* __restrict__ w, bf16x8* __restrict__ wf) {
    const int mt   = blockIdx.x >> 2;       // 0..39
    const int kt   = blockIdx.x & 3;        // 0..3
    const int lane = threadIdx.x;           // 0..63
    const int j  = mt >> 3;
    const int ot = mt & 7;
    const int o  = ot * 16 + (lane & 15);
    const int c0 = kt * 32 + (lane >> 4) * 8;
    const float* wp = w + ((size_t)o * 128 + c0) * 5 + j;
    bf16x8 f;
    #pragma unroll
    for (int e = 0; e < 8; ++e) f[e] = f2bf(wp[e * 5]);
    wf[(size_t)(mt * 4 + kt) * 64 + lane] = f;
}

// ---------------- main: one block per (n, h) row ----------------
// 512 threads = 8 waves = mh(2 channel-halves) x pt(4 pos-tiles).
// A = X (M = 16 positions), B = W (N = 16 channels): lane's acc f32x4 = 4
// consecutive w positions (pos = pt*16 + lg*4 + r) of channel ot*16 + l15.
// Per tap j: acc -> swizzled LDS [128 ch][64 pos] -> barrier -> linear
// readback -> coalesced 1KB NT dwordx4 stores. Shifts folded into LDS write
// (w-shift, j=1/3) or store row (h-shift, j=0/4) with zero-filled edges.
__global__ __launch_bounds__(512, 4)
void sconv_v4(const float* __restrict__ x, const bf16x8* __restrict__ wf,
              float* __restrict__ out) {
    __shared__ float lds[128 * 64];         // 32 KiB, row = ch, quad-swizzled

    const int bid = blockIdx.x;
    const int h = bid & 63;
    const int n = bid >> 6;

    const int t    = threadIdx.x;
    const int wave = t >> 6;
    const int lane = t & 63;
    const int mh   = wave >> 2;
    const int pt   = wave & 3;
    const int l15  = lane & 15;
    const int lg   = lane >> 4;
    const int pos  = pt * 16 + l15;         // gather position (A row = l15 map)

    // ---- gather X fragments (A operand), all in-bounds, kept in regs ----
    const float* xb = x + (size_t)n * 128 * 4096 + (size_t)(h * 64 + pos);
    bf16x8 xf[4];
    #pragma unroll
    for (int kt = 0; kt < 4; ++kt) {
        const float* xp = xb + (size_t)(kt * 32 + lg * 8) * 4096;
        bf16x8 f;
        #pragma unroll
        for (int e = 0; e < 8; ++e) f[e] = f2bf(xp[(size_t)e * 4096]);
        xf[kt] = f;
    }

    const int wq  = pt * 4 + lg;            // quad this lane's acc covers
    const int wp0 = pt * 16 + lg * 4;       // first position of that quad

    #pragma unroll
    for (int j = 0; j < 5; ++j) {
        // zero-fill the edge column for w-shifted taps
        if (j == 1 && t < 128) lds[t * 64 + ((t & 7) << 2)] = 0.f;          // ws=0
        if (j == 3 && t < 128) lds[t * 64 + ((15 ^ (t & 7)) << 2) + 3] = 0.f; // ws=63

        #pragma unroll
        for (int oi = 0; oi < 4; ++oi) {
            const int ot = mh * 4 + oi;
            const int ch = ot * 16 + l15;
            const bf16x8* wfp = wf + (size_t)((j * 8 + ot) * 4) * 64 + lane;

            f32x4 acc = {0.f, 0.f, 0.f, 0.f};
            #pragma unroll
            for (int kt = 0; kt < 4; ++kt)
                acc = __builtin_amdgcn_mfma_f32_16x16x32_bf16(
                    xf[kt], wfp[(size_t)kt * 64], acc, 0, 0, 0);

            if (j == 0 || j == 2 || j == 4) {
                f32x4 v;
                #pragma unroll
                for (int r = 0; r < 4; ++r) v[r] = relu(acc[r]);
                *reinterpret_cast<f32x4*>(
                    &lds[ch * 64 + ((wq ^ (ch & 7)) << 2)]) = v;
            } else {
                #pragma unroll
                for (int r = 0; r < 4; ++r) {
                    const int ws = wp0 + r + (j == 1 ? 1 : -1);
                    if ((unsigned)ws < 64u)
                        lds[ch * 64 + (((ws >> 2) ^ (ch & 7)) << 2) + (ws & 3)]
                            = relu(acc[r]);
                }
            }
        }
        __syncthreads();

        // ---- linear readback + coalesced NT stores ----
        const int  hs = (j == 0) ? ((h + 1) & 63)
                      : (j == 4) ? ((h + 63) & 63) : h;
        const bool zr = (j == 0 && h == 63) || (j == 4 && h == 0);

        #pragma unroll
        for (int i = 0; i < 4; ++i) {
            const int g  = i * 512 + t;
            const int ch = g >> 4;
            const int q  = g & 15;
            f32x4 v = *reinterpret_cast<const f32x4*>(
                &lds[ch * 64 + ((q ^ (ch & 7)) << 2)]);
            if (zr) v = f32x4{0.f, 0.f, 0.f, 0.f};
            __builtin_nontemporal_store(
                v, reinterpret_cast<f32x4*>(
                       out + (((size_t)n * 640 + j * 128 + ch) * 64 + hs) * 64
                           + q * 4));
        }
        if (j < 4) __syncthreads();
    }
}

// ---------------- fallback (R1 kernel) if workspace is too small ----------------
__global__ __launch_bounds__(512, 2)
void sconv_mfma(const float* __restrict__ x, const float* __restrict__ w,
                float* __restrict__ out) {
    __shared__ bf16x8 wfrag[8][4][64];
    const int bid = blockIdx.x;
    const int j   = bid % 5;
    const int hp  = (bid / 5) % 32;
    const int n   = bid / 160;
    const int t = threadIdx.x;
    for (int s = t; s < 2048; s += 512) {
        const int lane = s & 63;
        const int rest = s >> 6;
        const int mt   = rest >> 2;
        const int kt   = rest & 3;
        const int o    = mt * 16 + (lane & 15);
        const int c0   = kt * 32 + (lane >> 4) * 8;
        const float* wp = w + ((size_t)o * 128 + c0) * 5 + j;
        bf16x8 f;
        #pragma unroll
        for (int e = 0; e < 8; ++e) f[e] = f2bf(wp[e * 5]);
        wfrag[mt][kt][lane] = f;
    }
    __syncthreads();
    const int wave = t >> 6;
    const int lane = t & 63;
    const int l15  = lane & 15;
    const int lg   = lane >> 4;
    const int h    = hp * 2 + (wave >> 2);
    const int wcol = (wave & 3) * 16 + l15;
    const int dy[5] = {-1, 0, 0, 0, 1};
    const int dx[5] = { 0,-1, 0, 1, 0};
    const int hi = h + dy[j];
    const int wi = wcol + dx[j];
    const bool valid = ((unsigned)hi < 64u) && ((unsigned)wi < 64u);
    const int hic = hi < 0 ? 0 : (hi > 63 ? 63 : hi);
    const int wic = wi < 0 ? 0 : (wi > 63 ? 63 : wi);
    const float* xb = x + (size_t)n * 128 * 4096 + (size_t)(hic * 64 + wic);
    bf16x8 xf[4];
    #pragma unroll
    for (int kt = 0; kt < 4; ++kt) {
        const int c0 = kt * 32 + lg * 8;
        const float* xp = xb + (size_t)c0 * 4096;
        bf16x8 f;
        #pragma unroll
        for (int e = 0; e < 8; ++e) {
            float v = xp[(size_t)e * 4096];
            f[e] = f2bf(valid ? v : 0.0f);
        }
        xf[kt] = f;
    }
    f32x4 acc[8];
    #pragma unroll
    for (int mt = 0; mt < 8; ++mt) acc[mt] = f32x4{0.f, 0.f, 0.f, 0.f};
    #pragma unroll
    for (int kt = 0; kt < 4; ++kt)
        #pragma unroll
        for (int mt = 0; mt < 8; ++mt)
            acc[mt] = __builtin_amdgcn_mfma_f32_16x16x32_bf16(
                wfrag[mt][kt][lane], xf[kt], acc[mt], 0, 0, 0);
    float* ob = out + ((size_t)n * 640 + (size_t)j * 128) * 4096
                    + (size_t)(h * 64 + wcol);
    #pragma unroll
    for (int mt = 0; mt < 8; ++mt) {
        const int ch = mt * 16 + lg * 4;
        #pragma unroll
        for (int r = 0; r < 4; ++r) {
            float v = acc[mt][r];
            ob[(size_t)(ch + r) * 4096] = v > 0.f ? v : 0.f;
        }
    }
}

extern "C" void kernel_launch(void* const* d_in, const int* in_sizes, int n_in,
                              void* d_out, int out_size, void* d_ws, size_t ws_size,
                              hipStream_t stream) {
    const float* x = (const float*)d_in[0];   // [32,128,64,64] f32
    const float* w = (const float*)d_in[1];   // [128,128,5] f32
    float* out = (float*)d_out;               // [32,640,64,64] f32

    const size_t wf_bytes = (size_t)40 * 4 * 64 * sizeof(bf16x8);  // 160 KiB
    if (ws_size >= wf_bytes) {
        bf16x8* wf = (bf16x8*)d_ws;
        hipLaunchKernelGGL(prep_wfrag, dim3(160), dim3(64), 0, stream, w, wf);
        hipLaunchKernelGGL(sconv_v4, dim3(32 * 64), dim3(512), 0, stream,
                           x, wf, out);
    } else {
        hipLaunchKernelGGL(sconv_mfma, dim3(32 * 32 * 5), dim3(512), 0, stream,
                           x, w, out);
    }
}